// Round 6
// baseline (88.215 us; speedup 1.0000x reference)
//
#include <hip/hip_runtime.h>
#include <math.h>

#define IMG  512
#define TW   32
#define TH   128
#define EXTR 138         // TH + 10 haloed rows
#define HS   33          // hb stride: h-writes & v-reads <=2-way bank alias
#define NBLK 3072        // 16*4*48 tile blocks
#define NPIX 12582912.0  // 48*512*512

// Normalized 11-tap Gaussian, sigma=1.5 — inline literals
constexpr float G[11] = {
    0.00102838f, 0.00759876f, 0.03600077f, 0.10936069f, 0.21300554f,
    0.26601173f,
    0.21300554f, 0.10936069f, 0.03600077f, 0.00759876f, 0.00102838f};

// hb planes: 0=mean(x) 1=mean(y) 2=mean(x^2+y^2) 3=mean(xy)
__global__ __launch_bounds__(256) void ssim_tile_kernel(
    const float* __restrict__ x, const float* __restrict__ y,
    float* __restrict__ partial)
{
    __shared__ float hb[4][EXTR][HS];   // 72.86 KB -> 2 blocks/CU
    __shared__ float wsum[4];

    const int tid = threadIdx.x;
    const int bx = blockIdx.x, by = blockIdx.y;
    const int c0 = bx * TW, r0 = by * TH;
    const size_t ioff = (size_t)blockIdx.z * IMG * IMG;
    const float* __restrict__ xb = x + ioff;
    const float* __restrict__ yb = y + ioff;

    // rows needed: r0-5 .. r0+TH+4 ; cols: c0-8 .. c0+39
    const bool interior = (bx > 0) & (bx < 15) & (by > 0) & (by < 3);

    // ---- horizontal pass: 138 rows x 8 groups = 1104 tasks, loop x 256 ----
    for (int t = tid; t < EXTR * 8; t += 256) {
        const int row = t >> 3;         // 0..137
        const int g   = t & 7;          // 4-output col group
        const int gr  = r0 - 5 + row;
        const int gc0 = c0 - 8 + 4 * g; // first of 20 raw cols
        float wx[20], wy[20];
        if (interior) {
            const float* __restrict__ px = xb + gr * IMG + gc0;
            const float* __restrict__ py = yb + gr * IMG + gc0;
#pragma unroll
            for (int i = 0; i < 5; ++i) {
                float4 fx = *(const float4*)(px + 4 * i);
                float4 fy = *(const float4*)(py + 4 * i);
                wx[4*i+0] = fx.x; wx[4*i+1] = fx.y; wx[4*i+2] = fx.z; wx[4*i+3] = fx.w;
                wy[4*i+0] = fy.x; wy[4*i+1] = fy.y; wy[4*i+2] = fy.z; wy[4*i+3] = fy.w;
            }
        } else {
            const bool rok = ((unsigned)gr < IMG);
            const float* __restrict__ px = xb + gr * IMG;
            const float* __restrict__ py = yb + gr * IMG;
#pragma unroll
            for (int i = 0; i < 5; ++i) {
                int gc = gc0 + 4 * i;
                if (rok && gc >= 0 && gc + 3 < IMG) {
                    float4 fx = *(const float4*)(px + gc);
                    float4 fy = *(const float4*)(py + gc);
                    wx[4*i+0] = fx.x; wx[4*i+1] = fx.y; wx[4*i+2] = fx.z; wx[4*i+3] = fx.w;
                    wy[4*i+0] = fy.x; wy[4*i+1] = fy.y; wy[4*i+2] = fy.z; wy[4*i+3] = fy.w;
                } else {
#pragma unroll
                    for (int e = 0; e < 4; ++e) {
                        int c = gc + e;
                        bool ok = rok && ((unsigned)c < IMG);
                        wx[4*i+e] = ok ? px[c] : 0.f;
                        wy[4*i+e] = ok ? py[c] : 0.f;
                    }
                }
            }
        }
        // shared products for raw cols 3..16
        float pss[14], pxy[14];
#pragma unroll
        for (int j = 0; j < 14; ++j) {
            float a = wx[j + 3], b = wy[j + 3];
            pss[j] = fmaf(a, a, b * b);
            pxy[j] = a * b;
        }
        float ax[4] = {}, ay[4] = {}, ass[4] = {}, axy[4] = {};
#pragma unroll
        for (int e = 0; e < 4; ++e)
#pragma unroll
            for (int k = 0; k < 11; ++k) {
                ax[e]  = fmaf(G[k], wx[e + k + 3], ax[e]);
                ay[e]  = fmaf(G[k], wy[e + k + 3], ay[e]);
                ass[e] = fmaf(G[k], pss[e + k], ass[e]);
                axy[e] = fmaf(G[k], pxy[e + k], axy[e]);
            }
#pragma unroll
        for (int e = 0; e < 4; ++e) {
            int cc = 4 * g + e;
            hb[0][row][cc] = ax[e];
            hb[1][row][cc] = ay[e];
            hb[2][row][cc] = ass[e];
            hb[3][row][cc] = axy[e];
        }
    }
    __syncthreads();

    // ---- vertical pass: thread = col tx, 16 rows rb..rb+15 ----
    const int tx = tid & 31;
    const int rb = (tid >> 5) * 16;     // 0,16,...,112
    float vr[4][16];
#pragma unroll
    for (int q = 0; q < 4; ++q)
#pragma unroll
        for (int j = 0; j < 16; ++j) vr[q][j] = 0.f;
#pragma unroll
    for (int q = 0; q < 4; ++q)
#pragma unroll
        for (int k = 0; k < 26; ++k) {
            float v = hb[q][rb + k][tx];
#pragma unroll
            for (int j = 0; j < 16; ++j)
                if (k - j >= 0 && k - j <= 10)
                    vr[q][j] = fmaf(G[k - j], v, vr[q][j]);
        }

    // ---- pointwise SSIM + block reduction ----
    float lsum = 0.f;
#pragma unroll
    for (int j = 0; j < 16; ++j) {
        float mx = vr[0][j], my = vr[1][j];
        float mss = vr[2][j], mxy = vr[3][j];
        float mx2 = mx * mx, my2 = my * my, mxmy = mx * my;
        float num = (2.f * mxmy + 0.0001f) * (2.f * (mxy - mxmy) + 0.0009f);
        float den = (mx2 + my2 + 0.0001f) * ((mss - mx2 - my2) + 0.0009f);
        lsum += num * __builtin_amdgcn_rcpf(den);
    }
#pragma unroll
    for (int off = 32; off > 0; off >>= 1)
        lsum += __shfl_down(lsum, off, 64);
    if ((tid & 63) == 0) wsum[tid >> 6] = lsum;
    __syncthreads();
    if (tid == 0) {
        float s = wsum[0] + wsum[1] + wsum[2] + wsum[3];
        int bid = bx + 16 * (by + 4 * blockIdx.z);
        partial[bid] = s;                // plain store, no atomic
    }
}

__global__ __launch_bounds__(1024) void ssim_reduce_kernel(
    const float* __restrict__ partial, float* __restrict__ out)
{
    __shared__ double ws[16];
    const int tid = threadIdx.x;
    double s = 0.0;
#pragma unroll
    for (int i = 0; i < NBLK / 1024; ++i) s += (double)partial[tid + i * 1024];
#pragma unroll
    for (int off = 32; off > 0; off >>= 1)
        s += __shfl_down(s, off, 64);
    if ((tid & 63) == 0) ws[tid >> 6] = s;
    __syncthreads();
    if (tid == 0) {
        double t = 0.0;
#pragma unroll
        for (int w = 0; w < 16; ++w) t += ws[w];
        double mean = t / NPIX;
        out[0] = (float)(-log10(mean));  // loss
        out[1] = (float)mean;            // ssim_mean
    }
}

extern "C" void kernel_launch(void* const* d_in, const int* in_sizes, int n_in,
                              void* d_out, int out_size, void* d_ws, size_t ws_size,
                              hipStream_t stream)
{
    const float* x = (const float*)d_in[0];
    const float* y = (const float*)d_in[1];
    float* out     = (float*)d_out;
    float* partial = (float*)d_ws;      // 3072 floats, fully rewritten each call

    dim3 grid(IMG / TW, IMG / TH, 48);  // 16 x 4 x 48 = 3072 blocks
    ssim_tile_kernel<<<grid, 256, 0, stream>>>(x, y, partial);
    ssim_reduce_kernel<<<1, 1024, 0, stream>>>(partial, out);
}

// Round 7
// 73.410 us; speedup vs baseline: 1.2017x; 1.2017x over previous
//
#include <hip/hip_runtime.h>
#include <math.h>

#define IMG   512
#define TW    32
#define NSTRIP 8         // 32-row strips per block
#define BROWS 256        // output rows per block (by half-column)
#define EXTR  42         // rolling hb window rows
#define HS    33         // hb stride: all patterns <=2-way bank alias
#define NBLK  1536       // 16 * 2 * 48
#define NPIX  12582912.0 // 48*512*512

// Normalized 11-tap Gaussian, sigma=1.5 — inline literals
constexpr float G[11] = {
    0.00102838f, 0.00759876f, 0.03600077f, 0.10936069f, 0.21300554f,
    0.26601173f,
    0.21300554f, 0.10936069f, 0.03600077f, 0.00759876f, 0.00102838f};

// hb planes: 0=mean(x) 1=mean(y) 2=mean(x^2+y^2) 3=mean(xy)
// buffer row b holds h-conv of global row (strip_base - 5 + b)
__global__ __launch_bounds__(256) void ssim_tile_kernel(
    const float* __restrict__ x, const float* __restrict__ y,
    float* __restrict__ partial)
{
    __shared__ float hb[4][EXTR][HS];   // 21.66 KB -> 6 blocks/CU resident
    __shared__ float wsum[4];

    const int tid = threadIdx.x;
    const int bx = blockIdx.x, by = blockIdx.y;
    const int c0 = bx * TW;
    const int rbase0 = by * BROWS;
    const size_t ioff = (size_t)blockIdx.z * IMG * IMG;
    const float* __restrict__ xb = x + ioff;
    const float* __restrict__ yb = y + ioff;

    const bool icol = (bx > 0) & (bx < 15);

    // h-task: compute 4 h-outputs (cols 4g..4g+3) of global row grow,
    // store into buffer row bufrow.
    auto htask = [&](int bufrow, int grow, int g) {
        const int cc0 = 4 * g;
        if ((unsigned)grow >= IMG) {    // zero-pad rows outside image
#pragma unroll
            for (int q = 0; q < 4; ++q) {
                hb[q][bufrow][cc0 + 0] = 0.f; hb[q][bufrow][cc0 + 1] = 0.f;
                hb[q][bufrow][cc0 + 2] = 0.f; hb[q][bufrow][cc0 + 3] = 0.f;
            }
            return;
        }
        const int gc0 = c0 - 8 + cc0;   // first of 20 raw cols
        float wx[20], wy[20];
        if (icol) {
            const float* __restrict__ px = xb + grow * IMG + gc0;
            const float* __restrict__ py = yb + grow * IMG + gc0;
#pragma unroll
            for (int i = 0; i < 5; ++i) {
                float4 fx = *(const float4*)(px + 4 * i);
                float4 fy = *(const float4*)(py + 4 * i);
                wx[4*i+0] = fx.x; wx[4*i+1] = fx.y; wx[4*i+2] = fx.z; wx[4*i+3] = fx.w;
                wy[4*i+0] = fy.x; wy[4*i+1] = fy.y; wy[4*i+2] = fy.z; wy[4*i+3] = fy.w;
            }
        } else {
            const float* __restrict__ px = xb + grow * IMG;
            const float* __restrict__ py = yb + grow * IMG;
#pragma unroll
            for (int i = 0; i < 5; ++i) {
                int gc = gc0 + 4 * i;
                if (gc >= 0 && gc + 3 < IMG) {
                    float4 fx = *(const float4*)(px + gc);
                    float4 fy = *(const float4*)(py + gc);
                    wx[4*i+0] = fx.x; wx[4*i+1] = fx.y; wx[4*i+2] = fx.z; wx[4*i+3] = fx.w;
                    wy[4*i+0] = fy.x; wy[4*i+1] = fy.y; wy[4*i+2] = fy.z; wy[4*i+3] = fy.w;
                } else {
#pragma unroll
                    for (int e = 0; e < 4; ++e) {
                        int c = gc + e;
                        bool ok = ((unsigned)c < IMG);
                        wx[4*i+e] = ok ? px[c] : 0.f;
                        wy[4*i+e] = ok ? py[c] : 0.f;
                    }
                }
            }
        }
        float pss[14], pxy[14];         // shared products, raw cols 3..16
#pragma unroll
        for (int j = 0; j < 14; ++j) {
            float a = wx[j + 3], b = wy[j + 3];
            pss[j] = fmaf(a, a, b * b);
            pxy[j] = a * b;
        }
        float ax[4] = {}, ay[4] = {}, ass[4] = {}, axy[4] = {};
#pragma unroll
        for (int e = 0; e < 4; ++e)
#pragma unroll
            for (int k = 0; k < 11; ++k) {
                ax[e]  = fmaf(G[k], wx[e + k + 3], ax[e]);
                ay[e]  = fmaf(G[k], wy[e + k + 3], ay[e]);
                ass[e] = fmaf(G[k], pss[e + k], ass[e]);
                axy[e] = fmaf(G[k], pxy[e + k], axy[e]);
            }
#pragma unroll
        for (int e = 0; e < 4; ++e) {
            hb[0][bufrow][cc0 + e] = ax[e];
            hb[1][bufrow][cc0 + e] = ay[e];
            hb[2][bufrow][cc0 + e] = ass[e];
            hb[3][bufrow][cc0 + e] = axy[e];
        }
    };

    const int tx = tid & 31;
    const int rb = (tid >> 5) * 4;      // v-pass row group 0,4,...,28
    float lsum = 0.f;

    for (int s = 0; s < NSTRIP; ++s) {
        const int sbase = rbase0 + 32 * s;   // strip output row base
        if (s == 0) {
            // fill all 42 buffer rows: 336 tasks over 256 threads
            htask(tid >> 3, sbase - 5 + (tid >> 3), tid & 7);
            if (tid < 80) {
                int t = 256 + tid;
                htask(t >> 3, sbase - 5 + (t >> 3), t & 7);
            }
        } else {
            // carry: buffer rows 32..41 -> 0..9  (1280 = 4*10*32 moves)
#pragma unroll
            for (int k = 0; k < 5; ++k) {
                int t = tid + k * 256;
                int q = t / 320, rem = t - q * 320;
                int rr = rem >> 5, cc = rem & 31;
                hb[q][rr][cc] = hb[q][32 + rr][cc];   // disjoint rows, no race
            }
            __syncthreads();
            // 32 new h-rows into buffer rows 10..41: exactly 1 task/thread
            htask(10 + (tid >> 3), sbase + 5 + (tid >> 3), tid & 7);
        }
        __syncthreads();

        // v-pass: 4 outputs at tile rows rb..rb+3 (buffer rows rb+j+k)
        float vr[4][4];
#pragma unroll
        for (int q = 0; q < 4; ++q)
#pragma unroll
            for (int j = 0; j < 4; ++j) vr[q][j] = 0.f;
#pragma unroll
        for (int q = 0; q < 4; ++q)
#pragma unroll
            for (int k = 0; k < 14; ++k) {
                float v = hb[q][rb + k][tx];
#pragma unroll
                for (int j = 0; j < 4; ++j)
                    if (k - j >= 0 && k - j <= 10)
                        vr[q][j] = fmaf(G[k - j], v, vr[q][j]);
            }
#pragma unroll
        for (int j = 0; j < 4; ++j) {
            float mx = vr[0][j], my = vr[1][j];
            float mss = vr[2][j], mxy = vr[3][j];
            float mx2 = mx * mx, my2 = my * my, mxmy = mx * my;
            float num = (2.f * mxmy + 0.0001f) * (2.f * (mxy - mxmy) + 0.0009f);
            float den = (mx2 + my2 + 0.0001f) * ((mss - mx2 - my2) + 0.0009f);
            lsum += num * __builtin_amdgcn_rcpf(den);
        }
        __syncthreads();   // protect buffer rows before next strip's carry/h
    }

    // ---- block reduction -> plain store ----
#pragma unroll
    for (int off = 32; off > 0; off >>= 1)
        lsum += __shfl_down(lsum, off, 64);
    if ((tid & 63) == 0) wsum[tid >> 6] = lsum;
    __syncthreads();
    if (tid == 0) {
        float ssum = wsum[0] + wsum[1] + wsum[2] + wsum[3];
        int bid = bx + 16 * (by + 2 * blockIdx.z);
        partial[bid] = ssum;
    }
}

__global__ __launch_bounds__(1024) void ssim_reduce_kernel(
    const float* __restrict__ partial, float* __restrict__ out)
{
    __shared__ double ws[16];
    const int tid = threadIdx.x;
    double s = 0.0;
    for (int i = tid; i < NBLK; i += 1024) s += (double)partial[i];
#pragma unroll
    for (int off = 32; off > 0; off >>= 1)
        s += __shfl_down(s, off, 64);
    if ((tid & 63) == 0) ws[tid >> 6] = s;
    __syncthreads();
    if (tid == 0) {
        double t = 0.0;
#pragma unroll
        for (int w = 0; w < 16; ++w) t += ws[w];
        double mean = t / NPIX;
        out[0] = (float)(-log10(mean));  // loss
        out[1] = (float)mean;            // ssim_mean
    }
}

extern "C" void kernel_launch(void* const* d_in, const int* in_sizes, int n_in,
                              void* d_out, int out_size, void* d_ws, size_t ws_size,
                              hipStream_t stream)
{
    const float* x = (const float*)d_in[0];
    const float* y = (const float*)d_in[1];
    float* out     = (float*)d_out;
    float* partial = (float*)d_ws;      // 1536 floats, fully rewritten each call

    dim3 grid(16, 2, 48);               // 1536 blocks = 6/CU, fully resident
    ssim_tile_kernel<<<grid, 256, 0, stream>>>(x, y, partial);
    ssim_reduce_kernel<<<1, 1024, 0, stream>>>(partial, out);
}

// Round 8
// 67.020 us; speedup vs baseline: 1.3163x; 1.0953x over previous
//
#include <hip/hip_runtime.h>
#include <math.h>

#define IMG    512
#define TWD    64        // tile width
#define NSTRIP 8         // 32-row strips per block
#define BROWS  256       // output rows per block
#define WIN    42        // rolling hb window rows
#define HS     68        // hb row stride in floats: 272B (16B-aligned), 68%32=4
#define NBLK   768       // 8 * 2 * 48
#define NPIX   12582912.0

// Normalized 11-tap Gaussian, sigma=1.5 — inline literals
constexpr float G[11] = {
    0.00102838f, 0.00759876f, 0.03600077f, 0.10936069f, 0.21300554f,
    0.26601173f,
    0.21300554f, 0.10936069f, 0.03600077f, 0.00759876f, 0.00102838f};

// hb planes: 0=mean(x) 1=mean(y) 2=mean(x^2+y^2) 3=mean(xy)
// buffer row b holds h-conv of global row (strip_base - 5 + b)
__global__ __launch_bounds__(256, 3) void ssim_tile_kernel(
    const float* __restrict__ x, const float* __restrict__ y,
    float* __restrict__ partial)
{
    __shared__ float hb[4][WIN][HS];    // 45.7 KB -> 3 blocks/CU
    __shared__ float wsum[4];

    const int tid = threadIdx.x;
    const int bx = blockIdx.x, by = blockIdx.y;
    const int c0 = bx * TWD;
    const int rbase0 = by * BROWS;
    const size_t ioff = (size_t)blockIdx.z * IMG * IMG;
    const float* __restrict__ xb = x + ioff;
    const float* __restrict__ yb = y + ioff;

    const bool icol = (bx > 0) & (bx < 7);

    // h-task: 8 outputs (cols 8g..8g+7) of global row grow -> buffer row bufrow
    auto htask = [&](int bufrow, int grow, int g) {
        const int cc0 = 8 * g;
        float4 z4 = make_float4(0.f, 0.f, 0.f, 0.f);
        if ((unsigned)grow >= IMG) {    // zero-pad rows outside image
#pragma unroll
            for (int q = 0; q < 4; ++q) {
                *(float4*)&hb[q][bufrow][cc0]     = z4;
                *(float4*)&hb[q][bufrow][cc0 + 4] = z4;
            }
            return;
        }
        const int gc0 = c0 - 8 + cc0;   // first of 24 raw cols
        float wx[24], wy[24];
        if (icol) {
            const float* __restrict__ px = xb + grow * IMG + gc0;
            const float* __restrict__ py = yb + grow * IMG + gc0;
#pragma unroll
            for (int i = 0; i < 6; ++i) {
                float4 fx = *(const float4*)(px + 4 * i);
                float4 fy = *(const float4*)(py + 4 * i);
                wx[4*i+0] = fx.x; wx[4*i+1] = fx.y; wx[4*i+2] = fx.z; wx[4*i+3] = fx.w;
                wy[4*i+0] = fy.x; wy[4*i+1] = fy.y; wy[4*i+2] = fy.z; wy[4*i+3] = fy.w;
            }
        } else {
            const float* __restrict__ px = xb + grow * IMG;
            const float* __restrict__ py = yb + grow * IMG;
#pragma unroll
            for (int i = 0; i < 6; ++i) {
                int gc = gc0 + 4 * i;
                if (gc >= 0 && gc + 3 < IMG) {
                    float4 fx = *(const float4*)(px + gc);
                    float4 fy = *(const float4*)(py + gc);
                    wx[4*i+0] = fx.x; wx[4*i+1] = fx.y; wx[4*i+2] = fx.z; wx[4*i+3] = fx.w;
                    wy[4*i+0] = fy.x; wy[4*i+1] = fy.y; wy[4*i+2] = fy.z; wy[4*i+3] = fy.w;
                } else {
#pragma unroll
                    for (int e = 0; e < 4; ++e) {
                        int c = gc + e;
                        bool ok = ((unsigned)c < IMG);
                        wx[4*i+e] = ok ? px[c] : 0.f;
                        wy[4*i+e] = ok ? py[c] : 0.f;
                    }
                }
            }
        }
        float pss[18], pxy[18];         // shared products, raw cols 3..20
#pragma unroll
        for (int j = 0; j < 18; ++j) {
            float a = wx[j + 3], b = wy[j + 3];
            pss[j] = fmaf(a, a, b * b);
            pxy[j] = a * b;
        }
        float ax[8] = {}, ay[8] = {}, ass[8] = {}, axy[8] = {};
#pragma unroll
        for (int e = 0; e < 8; ++e)
#pragma unroll
            for (int k = 0; k < 11; ++k) {
                ax[e]  = fmaf(G[k], wx[e + k + 3], ax[e]);
                ay[e]  = fmaf(G[k], wy[e + k + 3], ay[e]);
                ass[e] = fmaf(G[k], pss[e + k], ass[e]);
                axy[e] = fmaf(G[k], pxy[e + k], axy[e]);
            }
        *(float4*)&hb[0][bufrow][cc0]     = make_float4(ax[0], ax[1], ax[2], ax[3]);
        *(float4*)&hb[0][bufrow][cc0 + 4] = make_float4(ax[4], ax[5], ax[6], ax[7]);
        *(float4*)&hb[1][bufrow][cc0]     = make_float4(ay[0], ay[1], ay[2], ay[3]);
        *(float4*)&hb[1][bufrow][cc0 + 4] = make_float4(ay[4], ay[5], ay[6], ay[7]);
        *(float4*)&hb[2][bufrow][cc0]     = make_float4(ass[0], ass[1], ass[2], ass[3]);
        *(float4*)&hb[2][bufrow][cc0 + 4] = make_float4(ass[4], ass[5], ass[6], ass[7]);
        *(float4*)&hb[3][bufrow][cc0]     = make_float4(axy[0], axy[1], axy[2], axy[3]);
        *(float4*)&hb[3][bufrow][cc0 + 4] = make_float4(axy[4], axy[5], axy[6], axy[7]);
    };

    const int cg = tid & 31;            // column pair: cols 2cg, 2cg+1
    const int rb = (tid >> 5) * 4;      // v-pass rows rb..rb+3
    float lsum = 0.f;

    for (int s = 0; s < NSTRIP; ++s) {
        const int sbase = rbase0 + 32 * s;
        if (s == 0) {
            // fill all 42 buffer rows: 336 tasks
            htask(tid >> 3, sbase - 5 + (tid >> 3), tid & 7);
            if (tid < 80) {
                int t = 256 + tid;
                htask(t >> 3, sbase - 5 + (t >> 3), t & 7);
            }
        } else {
            // carry rows 32..41 -> 0..9 : 640 float4 moves
#pragma unroll
            for (int k = 0; k < 3; ++k) {
                int idx = tid + k * 256;
                if (idx < 640) {
                    int q = idx / 160, rem = idx - q * 160;
                    int rr = rem >> 4, c4 = rem & 15;
                    *(float4*)&hb[q][rr][4 * c4] = *(const float4*)&hb[q][32 + rr][4 * c4];
                }
            }
            __syncthreads();
            // 32 new h-rows into buffer rows 10..41: exactly 1 task/thread
            htask(10 + (tid >> 3), sbase + 5 + (tid >> 3), tid & 7);
        }
        __syncthreads();

        // v-pass: 2 cols x 4 rows per thread, float2 LDS reads
        float vr[4][4][2];
#pragma unroll
        for (int q = 0; q < 4; ++q)
#pragma unroll
            for (int j = 0; j < 4; ++j) { vr[q][j][0] = 0.f; vr[q][j][1] = 0.f; }
#pragma unroll
        for (int q = 0; q < 4; ++q)
#pragma unroll
            for (int k = 0; k < 14; ++k) {
                float2 v = *(const float2*)&hb[q][rb + k][2 * cg];
#pragma unroll
                for (int j = 0; j < 4; ++j)
                    if (k - j >= 0 && k - j <= 10) {
                        vr[q][j][0] = fmaf(G[k - j], v.x, vr[q][j][0]);
                        vr[q][j][1] = fmaf(G[k - j], v.y, vr[q][j][1]);
                    }
            }
#pragma unroll
        for (int j = 0; j < 4; ++j)
#pragma unroll
            for (int e = 0; e < 2; ++e) {
                float mx = vr[0][j][e], my = vr[1][j][e];
                float mss = vr[2][j][e], mxy = vr[3][j][e];
                float mx2 = mx * mx, my2 = my * my, mxmy = mx * my;
                float num = (2.f * mxmy + 0.0001f) * (2.f * (mxy - mxmy) + 0.0009f);
                float den = (mx2 + my2 + 0.0001f) * ((mss - mx2 - my2) + 0.0009f);
                lsum += num * __builtin_amdgcn_rcpf(den);
            }
        __syncthreads();   // protect window before next strip's carry
    }

    // ---- block reduction -> plain store ----
#pragma unroll
    for (int off = 32; off > 0; off >>= 1)
        lsum += __shfl_down(lsum, off, 64);
    if ((tid & 63) == 0) wsum[tid >> 6] = lsum;
    __syncthreads();
    if (tid == 0) {
        float ssum = wsum[0] + wsum[1] + wsum[2] + wsum[3];
        int bid = bx + 8 * (by + 2 * blockIdx.z);
        partial[bid] = ssum;
    }
}

__global__ __launch_bounds__(1024) void ssim_reduce_kernel(
    const float* __restrict__ partial, float* __restrict__ out)
{
    __shared__ double ws[16];
    const int tid = threadIdx.x;
    double s = 0.0;
    for (int i = tid; i < NBLK; i += 1024) s += (double)partial[i];
#pragma unroll
    for (int off = 32; off > 0; off >>= 1)
        s += __shfl_down(s, off, 64);
    if ((tid & 63) == 0) ws[tid >> 6] = s;
    __syncthreads();
    if (tid == 0) {
        double t = 0.0;
#pragma unroll
        for (int w = 0; w < 16; ++w) t += ws[w];
        double mean = t / NPIX;
        out[0] = (float)(-log10(mean));  // loss
        out[1] = (float)mean;            // ssim_mean
    }
}

extern "C" void kernel_launch(void* const* d_in, const int* in_sizes, int n_in,
                              void* d_out, int out_size, void* d_ws, size_t ws_size,
                              hipStream_t stream)
{
    const float* x = (const float*)d_in[0];
    const float* y = (const float*)d_in[1];
    float* out     = (float*)d_out;
    float* partial = (float*)d_ws;      // 768 floats, fully rewritten each call

    dim3 grid(8, 2, 48);                // 768 blocks = exactly 3/CU
    ssim_tile_kernel<<<grid, 256, 0, stream>>>(x, y, partial);
    ssim_reduce_kernel<<<1, 1024, 0, stream>>>(partial, out);
}